// Round 2
// baseline (293.322 us; speedup 1.0000x reference)
//
#include <hip/hip_runtime.h>

#define N0        200000
#define N1        25000
#define N2        5000
#define FANOUT    16
#define IN_FEATS  500
#define NH        128
#define NC        47

#define K_PAD     512          // IN_FEATS padded to MFMA K granularity
#define M_PAD     25088        // N1 padded to 128*196

typedef __attribute__((ext_vector_type(4))) float f32x4;
typedef __attribute__((ext_vector_type(8))) short bf16x8;
typedef __attribute__((ext_vector_type(4))) unsigned int uint4_;

__device__ __forceinline__ unsigned short f2bf(float f) {
    unsigned int u = __builtin_bit_cast(unsigned int, f);
    u += 0x7fffu + ((u >> 16) & 1u);          // RNE
    return (unsigned short)(u >> 16);
}
__device__ __forceinline__ float bf2f(unsigned short h) {
    unsigned int u = ((unsigned int)h) << 16;
    return __builtin_bit_cast(float, u);
}

// ---------------------------------------------------------------------------
// k1a: gather-mean over features -> m0 bf16 [M_PAD][K_PAD] (zero-padded).
// One wave per output row; lane covers 8 consecutive features (32 B/lane).
// ---------------------------------------------------------------------------
__global__ __launch_bounds__(256) void k1a_gather(
    const float* __restrict__ features,   // [N0, IN_FEATS]
    const int*   __restrict__ src0,       // [N1, FANOUT]
    unsigned short* __restrict__ m0)      // [M_PAD, K_PAD] bf16
{
    const int lane = threadIdx.x & 63;
    const int row  = blockIdx.x * 4 + (threadIdx.x >> 6);
    const int f0   = lane * 8;

    float acc[8] = {0.f,0.f,0.f,0.f,0.f,0.f,0.f,0.f};

    if (row < N1) {
        // wave-uniform index base -> scalar loads for neighbor ids
        const int rbase = __builtin_amdgcn_readfirstlane(row) * FANOUT;
        const bool v0 = (f0 < IN_FEATS);          // f0..f0+3 valid (f0<=496)
        const bool v1 = (f0 + 7 < IN_FEATS);      // f0..f0+7 valid
        #pragma unroll
        for (int j = 0; j < FANOUT; ++j) {
            const int nb = src0[rbase + j];
            const float* p = features + (size_t)nb * IN_FEATS + f0;
            if (v1) {
                f32x4 a = *(const f32x4*)p;
                f32x4 b = *(const f32x4*)(p + 4);
                acc[0] += a.x; acc[1] += a.y; acc[2] += a.z; acc[3] += a.w;
                acc[4] += b.x; acc[5] += b.y; acc[6] += b.z; acc[7] += b.w;
            } else if (v0) {
                f32x4 a = *(const f32x4*)p;
                acc[0] += a.x; acc[1] += a.y; acc[2] += a.z; acc[3] += a.w;
            }
        }
    }
    // rows >= N1 (padding) write zeros; pad features also zero.
    unsigned int w0 = (unsigned int)f2bf(acc[0] * 0.0625f) | ((unsigned int)f2bf(acc[1] * 0.0625f) << 16);
    unsigned int w1 = (unsigned int)f2bf(acc[2] * 0.0625f) | ((unsigned int)f2bf(acc[3] * 0.0625f) << 16);
    unsigned int w2 = (unsigned int)f2bf(acc[4] * 0.0625f) | ((unsigned int)f2bf(acc[5] * 0.0625f) << 16);
    unsigned int w3 = (unsigned int)f2bf(acc[6] * 0.0625f) | ((unsigned int)f2bf(acc[7] * 0.0625f) << 16);
    uint4_ pack = {w0, w1, w2, w3};
    *(uint4_*)(m0 + (size_t)row * K_PAD + f0) = pack;
}

// ---------------------------------------------------------------------------
// k1b: bf16 MFMA GEMM  h1 = m0 @ W1 + b1, then h1cat = [h1, relu(h1)] (bf16).
// Block: 256 thr (4 waves), 128 rows; wave = 32 rows x 128 cols.
// W1^T staged per 128-k chunk in LDS (XOR-swizzled), A-frags from global m0.
// ---------------------------------------------------------------------------
__global__ __launch_bounds__(256) void k1b_gemm(
    const unsigned short* __restrict__ m0,    // [M_PAD, K_PAD] bf16
    const float* __restrict__ W1,             // [IN_FEATS, NH] f32
    const float* __restrict__ b1,             // [NH]
    unsigned short* __restrict__ h1cat)       // [N1, 2*NH] bf16
{
    __shared__ unsigned short Wt[128 * 128];  // [col][k-chunk] bf16, swizzled, 32 KB

    const int tid  = threadIdx.x;
    const int lane = tid & 63;
    const int wv   = tid >> 6;                // 0..3
    const int l15  = lane & 15;
    const int lq   = lane >> 4;               // 0..3
    const int rowbase = blockIdx.x * 128 + wv * 32;

    f32x4 acc[2][8];
    #pragma unroll
    for (int m = 0; m < 2; ++m)
        #pragma unroll
        for (int n = 0; n < 8; ++n) acc[m][n] = (f32x4){0.f,0.f,0.f,0.f};

    for (int chunk = 0; chunk < 4; ++chunk) {
        const int k0 = chunk * 128;
        // stage W^T chunk: wave wv covers cols [wv*32, wv*32+32); lane packs k-pair
        {
            const int k = k0 + 2 * lane;
            #pragma unroll
            for (int i = 0; i < 32; ++i) {
                const int c  = wv * 32 + i;
                const float w0f = (k     < IN_FEATS) ? W1[(size_t)k * NH + c]       : 0.f;
                const float w1f = (k + 1 < IN_FEATS) ? W1[(size_t)(k + 1) * NH + c] : 0.f;
                const unsigned int p = (unsigned int)f2bf(w0f) | ((unsigned int)f2bf(w1f) << 16);
                const int boff = c * 256 + ((4 * lane) ^ ((c & 7) << 4));
                *(unsigned int*)((char*)Wt + boff) = p;
            }
        }
        __syncthreads();
        #pragma unroll
        for (int ks = 0; ks < 4; ++ks) {
            const int klocal = ks * 32 + lq * 8;   // element offset within chunk
            bf16x8 a0 = *(const bf16x8*)(m0 + (size_t)(rowbase +      l15) * K_PAD + k0 + klocal);
            bf16x8 a1 = *(const bf16x8*)(m0 + (size_t)(rowbase + 16 + l15) * K_PAD + k0 + klocal);
            #pragma unroll
            for (int nt = 0; nt < 8; ++nt) {
                const int col  = nt * 16 + l15;
                const int boff = col * 256 + ((klocal * 2) ^ ((col & 7) << 4));
                bf16x8 b = *(const bf16x8*)((const char*)Wt + boff);
                acc[0][nt] = __builtin_amdgcn_mfma_f32_16x16x32_bf16(a0, b, acc[0][nt], 0, 0, 0);
                acc[1][nt] = __builtin_amdgcn_mfma_f32_16x16x32_bf16(a1, b, acc[1][nt], 0, 0, 0);
            }
        }
        __syncthreads();
    }

    // epilogue: bias, concat(h, relu(h)) as bf16
    #pragma unroll
    for (int nt = 0; nt < 8; ++nt) {
        const int col = nt * 16 + l15;
        const float bias = b1[col];
        #pragma unroll
        for (int m = 0; m < 2; ++m) {
            #pragma unroll
            for (int r = 0; r < 4; ++r) {
                const int row = rowbase + m * 16 + lq * 4 + r;
                if (row < N1) {
                    const float h = acc[m][nt][r] + bias;
                    h1cat[(size_t)row * 256 + col]       = f2bf(h);
                    h1cat[(size_t)row * 256 + 128 + col] = f2bf(h > 0.f ? h : 0.f);
                }
            }
        }
    }
}

// ---------------------------------------------------------------------------
// k2: gather-mean over bf16 h1cat + f32 GEMM [8x256]@[256x47] + bias.
// ---------------------------------------------------------------------------
__global__ __launch_bounds__(256) void k2_fused(
    const unsigned short* __restrict__ h1cat, // [N1, 256] bf16
    const int*   __restrict__ src1,           // [N2, FANOUT]
    const float* __restrict__ W2,             // [256, NC]
    const float* __restrict__ b2,             // [NC]
    float*       __restrict__ out)            // [N2, NC]
{
    __shared__ float sm[8][256];              // 8 KB

    const int tid = threadIdx.x;
    const int r   = tid >> 5;                 // 0..7
    const int s   = tid & 31;                 // 0..31
    const int row = blockIdx.x * 8 + r;

    // gather: thread covers 8 consecutive cols of its row (16 B bf16 loads)
    float acc[8] = {0.f,0.f,0.f,0.f,0.f,0.f,0.f,0.f};
    #pragma unroll
    for (int j = 0; j < FANOUT; ++j) {
        const int nb = src1[row * FANOUT + j];
        bf16x8 v = *(const bf16x8*)(h1cat + (size_t)nb * 256 + s * 8);
        #pragma unroll
        for (int e = 0; e < 8; ++e) acc[e] += bf2f((unsigned short)v[e]);
    }
    #pragma unroll
    for (int e = 0; e < 8; ++e) sm[r][s * 8 + e] = acc[e] * 0.0625f;
    __syncthreads();

    // GEMM: thread computes cols s and s+32 (if <47) of its row
    const int c0 = s, c1 = s + 32;
    float o0 = b2[c0];
    float o1 = (c1 < NC) ? b2[c1] : 0.f;
    for (int k = 0; k < 256; k += 4) {
        f32x4 mv = *(const f32x4*)&sm[r][k];
        #pragma unroll
        for (int e = 0; e < 4; ++e) {
            const float* wrow = W2 + (size_t)(k + e) * NC;
            o0 += mv[e] * wrow[c0];
            if (c1 < NC) o1 += mv[e] * wrow[c1];
        }
    }
    out[(size_t)row * NC + c0] = o0;
    if (c1 < NC) out[(size_t)row * NC + c1] = o1;
}

extern "C" void kernel_launch(void* const* d_in, const int* in_sizes, int n_in,
                              void* d_out, int out_size, void* d_ws, size_t ws_size,
                              hipStream_t stream)
{
    const float* features = (const float*)d_in[0];
    const int*   src0     = (const int*)  d_in[1];
    const int*   src1     = (const int*)  d_in[2];
    const float* W1       = (const float*)d_in[3];
    const float* b1       = (const float*)d_in[4];
    const float* W2       = (const float*)d_in[5];
    const float* b2       = (const float*)d_in[6];
    float*       out      = (float*)d_out;

    unsigned short* m0    = (unsigned short*)d_ws;            // M_PAD*K_PAD bf16
    unsigned short* h1cat = m0 + (size_t)M_PAD * K_PAD;       // N1*256 bf16

    hipLaunchKernelGGL(k1a_gather, dim3(M_PAD / 4),  dim3(256), 0, stream,
                       features, src0, m0);
    hipLaunchKernelGGL(k1b_gemm,  dim3(M_PAD / 128), dim3(256), 0, stream,
                       m0, W1, b1, h1cat);
    hipLaunchKernelGGL(k2_fused,  dim3(N2 / 8),      dim3(256), 0, stream,
                       h1cat, src1, W2, b2, out);
}